// Round 8
// baseline (313.644 us; speedup 1.0000x reference)
//
#include <hip/hip_runtime.h>
#include <hip/hip_bf16.h>
#include <hip/hip_fp16.h>
#include <math.h>

#define N_NODES 50000
#define F_IN 256
#define F_OUT 128
#define NBUK ((N_NODES + 255) >> 8)   // 196 buckets of 256 dsts
#define BUK_CAP 8192                  // >> max bucket edge count (Poisson ~4096)

typedef __attribute__((ext_vector_type(8))) short bf16x8;
typedef __attribute__((ext_vector_type(4))) float f32x4;
typedef _Float16 h2 __attribute__((ext_vector_type(2)));

static __device__ __forceinline__ h2 u2h2(unsigned u) {
    union { unsigned u; h2 h; } x; x.u = u; return x.h;
}
static __device__ __forceinline__ short f2bf(float f) {
    unsigned u = __float_as_uint(f);
    unsigned r = (u + 0x7FFFu + ((u >> 16) & 1u)) >> 16;  // RNE
    return (short)r;
}
static __device__ __forceinline__ float fast_tanh(float x) {
    float e = __expf(2.0f * x);
    return 1.0f - 2.0f / (e + 1.0f);
}

// ---------------------------------------------------------------------------
// K1: detect int64 vs int32 edge_index layout.
__global__ __launch_bounds__(64) void k_detect(const int* __restrict__ ei,
                                               int* __restrict__ flag) {
    if (threadIdx.x == 0) {
        int orv = 0;
        for (int i = 0; i < 64; i++) orv |= ei[2 * i + 1];
        flag[0] = (orv == 0) ? 1 : 0;  // 1 => int64
    }
}

// K2 (fused): decode + pack + block-aggregated append into per-bucket regions
// stage2[b*BUK_CAP ...]. bcursor (padded, 1 per 64B) ends as per-bucket count.
__global__ __launch_bounds__(1024) void k_histA(const void* __restrict__ ei,
                                                const float* __restrict__ ew,
                                                const int* __restrict__ flag,
                                                int* __restrict__ bcursor,
                                                int2* __restrict__ stage2, int E) {
    __shared__ int hist[NBUK];
    __shared__ int base[NBUK];
    int t = threadIdx.x;
    int isI64 = flag[0];
    for (long long c0 = (long long)blockIdx.x * 4096; c0 < E;
         c0 += (long long)gridDim.x * 4096) {
        if (t < NBUK) hist[t] = 0;
        __syncthreads();
        int2 v[4];
        int b[4], r[4];
        #pragma unroll
        for (int j = 0; j < 4; j++) {
            long long e = c0 + j * 1024 + t;
            if (e < E) {
                int s, d;
                if (isI64) {
                    const long long* p = (const long long*)ei;
                    s = (int)p[e];
                    d = (int)p[(size_t)E + e];
                } else {
                    const int* p = (const int*)ei;
                    s = p[e];
                    d = p[(size_t)E + e];
                }
                unsigned wh = __half_as_ushort(__float2half(ew[e]));
                v[j] = make_int2(s | ((d & 255) << 16) | ((d >> 8) << 24), (int)wh);
                b[j] = d >> 8;
            } else {
                b[j] = -1;
            }
        }
        #pragma unroll
        for (int j = 0; j < 4; j++)
            if (b[j] >= 0) r[j] = atomicAdd(&hist[b[j]], 1);
        __syncthreads();
        if (t < NBUK) {
            int h = hist[t];
            base[t] = h ? atomicAdd(&bcursor[t << 4], h) : 0;
        }
        __syncthreads();
        #pragma unroll
        for (int j = 0; j < 4; j++)
            if (b[j] >= 0)
                stage2[(size_t)b[j] * BUK_CAP + base[b[j]] + r[j]] = v[j];
        __syncthreads();
    }
}

// K3: exclusive scan of 196 bucket counts -> bbase; write rstart[N]=E.
__global__ __launch_bounds__(256) void k_scanB(const int* __restrict__ bcursor,
                                               int* __restrict__ bbase,
                                               int* __restrict__ rstart, int E) {
    __shared__ int sh[256];
    int t = threadIdx.x;
    int c = (t < NBUK) ? bcursor[t << 4] : 0;
    int val = c;
    sh[t] = val;
    __syncthreads();
    for (int off = 1; off < 256; off <<= 1) {
        int x = (t >= off) ? sh[t - off] : 0;
        __syncthreads();
        val += x;
        sh[t] = val;
        __syncthreads();
    }
    if (t < NBUK) bbase[t] = val - c;
    if (t == 0) rstart[N_NODES] = E;
}

// K4: per-bucket: LDS dst-histogram + scan -> rstart, then rank-scatter to ep.
__global__ __launch_bounds__(256) void k_partB(const int* __restrict__ bcursor,
                                               const int* __restrict__ bbase,
                                               const int2* __restrict__ stage2,
                                               int2* __restrict__ ep,
                                               int* __restrict__ rstart) {
    __shared__ int h[256];
    __shared__ int roff[256];
    __shared__ int sh[256];
    int b = blockIdx.x, t = threadIdx.x;
    int cnt = bcursor[b << 4];
    int base = bbase[b];
    const int2* src = stage2 + (size_t)b * BUK_CAP;
    h[t] = 0;
    __syncthreads();
    for (int i = t; i < cnt; i += 256) atomicAdd(&h[(src[i].x >> 16) & 255], 1);
    __syncthreads();
    int c = h[t];
    int val = c;
    sh[t] = val;
    __syncthreads();
    for (int off = 1; off < 256; off <<= 1) {
        int x = (t >= off) ? sh[t - off] : 0;
        __syncthreads();
        val += x;
        sh[t] = val;
        __syncthreads();
    }
    roff[t] = val - c;
    int dst = (b << 8) + t;
    if (dst < N_NODES) rstart[dst] = base + (val - c);
    h[t] = 0;
    __syncthreads();
    for (int i = t; i < cnt; i += 256) {
        int2 v = src[i];
        int dl = (v.x >> 16) & 255;
        int r = atomicAdd(&h[dl], 1);
        ep[base + roff[dl] + r] = make_int2(v.x & 0xFFFF, v.y);
    }
}

// ---------------------------------------------------------------------------
// K5: W[256][128] fp32 -> Wt[128][256] bf16 (transposed).
__global__ __launch_bounds__(256) void k_wconv(const float* __restrict__ W,
                                               short* __restrict__ Wt) {
    int id = blockIdx.x * 256 + threadIdx.x;
    if (id >= F_IN * F_OUT) return;
    int n = id >> 8;
    int k = id & 255;
    Wt[id] = f2bf(W[(size_t)k * F_OUT + n]);
}

// K6: H[M,128] = tanh(A[M,256] @ W) via bf16 MFMA (unchanged from round 7).
#define RED_STRIDE 36
__global__ __launch_bounds__(256) void k_gemm_mfma(const float* __restrict__ A,
                                                   const short* __restrict__ Wt,
                                                   __half* __restrict__ H, int M) {
    __shared__ float red[2 * 64 * RED_STRIDE];  // 18.4 KB
    int wave = threadIdx.x >> 6;
    int lane = threadIdx.x & 63;
    int lm = lane & 15;
    int kgrp = lane >> 4;
    int rowhalf = wave >> 1;
    int khalf = wave & 1;
    int m = blockIdx.x * 32 + rowhalf * 16 + lm;
    int am = (m < M) ? m : (M - 1);
    const float* arow = A + (size_t)am * F_IN + khalf * 128 + kgrp * 8;

    float4 a[8];
    #pragma unroll
    for (int k0 = 0; k0 < 4; k0++) {
        a[2 * k0]     = *(const float4*)(arow + k0 * 32);
        a[2 * k0 + 1] = *(const float4*)(arow + k0 * 32 + 4);
    }

    f32x4 acc[8] = {};
    #pragma unroll
    for (int k0 = 0; k0 < 4; k0++) {
        bf16x8 af;
        af[0] = f2bf(a[2 * k0].x);     af[1] = f2bf(a[2 * k0].y);
        af[2] = f2bf(a[2 * k0].z);     af[3] = f2bf(a[2 * k0].w);
        af[4] = f2bf(a[2 * k0 + 1].x); af[5] = f2bf(a[2 * k0 + 1].y);
        af[6] = f2bf(a[2 * k0 + 1].z); af[7] = f2bf(a[2 * k0 + 1].w);
        int koff = khalf * 128 + k0 * 32 + kgrp * 8;
        #pragma unroll
        for (int j = 0; j < 8; j++) {
            bf16x8 bf = *(const bf16x8*)(Wt + (size_t)(j * 16 + lm) * F_IN + koff);
            acc[j] = __builtin_amdgcn_mfma_f32_16x16x32_bf16(af, bf, acc[j], 0, 0, 0);
        }
    }

    float* myred = &red[(rowhalf * 64 + lane) * RED_STRIDE];
    if (khalf == 1) {
        #pragma unroll
        for (int j = 0; j < 8; j++) *(f32x4*)(myred + j * 4) = acc[j];
    }
    __syncthreads();
    if (khalf == 0) {
        int rbase = blockIdx.x * 32 + rowhalf * 16 + kgrp * 4;
        #pragma unroll
        for (int j = 0; j < 8; j++) {
            f32x4 o = *(const f32x4*)(myred + j * 4);
            #pragma unroll
            for (int jj = 0; jj < 4; jj++) {
                int r = rbase + jj;
                if (r < M)
                    H[(size_t)r * F_OUT + j * 16 + lm] =
                        __float2half(fast_tanh(acc[j][jj] + o[jj]));
            }
        }
    }
}

// ---------------------------------------------------------------------------
// K7: SPMM hop, src-sliced for L2 residency. Wave owns up to 3 pairs (6 nodes);
// edge chunks (<=64/node) live in registers; 7 passes over src slices of 8192
// rows (2MB fp16 < 4MB XCD-L2); all waves resident & phase-aligned. Per pass:
// ballot matching edges, walk mask 4-wide with batched gathers.
#define HOP_BLOCKS 2084
#define rl __builtin_amdgcn_readlane
__global__ __launch_bounds__(256, 8) void k_hop(const int* __restrict__ rstart,
                                                const int2* __restrict__ ep,
                                                const unsigned* __restrict__ xin,
                                                void* __restrict__ xoutv,
                                                const float* __restrict__ bias,
                                                int last) {
    int wid = blockIdx.x * 4 + (threadIdx.x >> 6);
    int lane = threadIdx.x & 63;
    int nw = gridDim.x << 2;  // 8336 waves; pairs {wid, wid+nw, wid+2nw}

#define DOT(hv, wj, ax, ay) {                                               \
        h2 h_ = u2h2(hv);                                                   \
        ax = __builtin_amdgcn_fdot2(h_, u2h2((unsigned)(wj)), ax, false);   \
        ay = __builtin_amdgcn_fdot2(h_, u2h2(((unsigned)(wj)) << 16), ay, false); }

    int2 ev[6];
    float ax[6], ay[6];
    #pragma unroll
    for (int q = 0; q < 6; q++) {
        int pair = wid + (q >> 1) * nw;
        int2 e2 = make_int2(0x0000FFFF, 0);  // sentinel: slice 7, never matches
        if (pair < 25000) {
            int node = 2 * pair + (q & 1);
            int s = rstart[node];
            int e = rstart[node + 1];
            int n = e - s;
            n = (n > 64) ? 64 : n;
            if (lane < n) e2 = ep[s + lane];
        }
        ev[q] = e2;
        ax[q] = 0.f;
        ay[q] = 0.f;
    }

    for (int pass = 0; pass < 7; ++pass) {
        #pragma unroll
        for (int q = 0; q < 6; q++) {
            unsigned long long mask = __ballot((ev[q].x >> 13) == pass);
            while (mask) {
                int j0 = __builtin_ctzll(mask);
                unsigned long long m_ = mask & (mask - 1);
                int j1 = j0, j2 = j0, j3 = j0;
                if (m_) {
                    j1 = __builtin_ctzll(m_); m_ &= m_ - 1;
                    if (m_) {
                        j2 = __builtin_ctzll(m_); m_ &= m_ - 1;
                        if (m_) { j3 = __builtin_ctzll(m_); m_ &= m_ - 1; }
                    }
                }
                mask = m_;
                int s0 = rl(ev[q].x, j0), s1 = rl(ev[q].x, j1);
                int s2 = rl(ev[q].x, j2), s3 = rl(ev[q].x, j3);
                unsigned w0 = (unsigned)rl(ev[q].y, j0);
                unsigned w1 = (j1 != j0) ? (unsigned)rl(ev[q].y, j1) : 0u;
                unsigned w2 = (j2 != j0) ? (unsigned)rl(ev[q].y, j2) : 0u;
                unsigned w3 = (j3 != j0) ? (unsigned)rl(ev[q].y, j3) : 0u;
                unsigned g0 = xin[(size_t)s0 * 64 + lane];
                unsigned g1 = xin[(size_t)s1 * 64 + lane];
                unsigned g2 = xin[(size_t)s2 * 64 + lane];
                unsigned g3 = xin[(size_t)s3 * 64 + lane];
                DOT(g0, w0, ax[q], ay[q])
                DOT(g1, w1, ax[q], ay[q])
                DOT(g2, w2, ax[q], ay[q])
                DOT(g3, w3, ax[q], ay[q])
            }
        }
    }

    // long-row fallback (deg > 64; astronomically rare for this graph)
    #pragma unroll
    for (int q = 0; q < 6; q++) {
        int pair = wid + (q >> 1) * nw;
        if (pair >= 25000) continue;
        int node = 2 * pair + (q & 1);
        int s = rstart[node];
        int e = rstart[node + 1];
        for (int i = s + 64; i < e; ++i) {
            int2 t2 = ep[i];
            unsigned g = xin[(size_t)t2.x * 64 + lane];
            DOT(g, (unsigned)t2.y, ax[q], ay[q])
        }
    }

    #pragma unroll
    for (int q = 0; q < 6; q++) {
        int pair = wid + (q >> 1) * nw;
        if (pair >= 25000) continue;
        int node = 2 * pair + (q & 1);
        if (last) {
            float bx = bias[2 * lane], by = bias[2 * lane + 1];
            ((float2*)xoutv)[(size_t)node * 64 + lane] =
                make_float2(ax[q] + bx, ay[q] + by);
        } else {
            ((__half2*)xoutv)[(size_t)node * 64 + lane] =
                __floats2half2_rn(ax[q], ay[q]);
        }
    }
#undef DOT
}
#undef rl

// ---------------------------------------------------------------------------
extern "C" void kernel_launch(void* const* d_in, const int* in_sizes, int n_in,
                              void* d_out, int out_size, void* d_ws, size_t ws_size,
                              hipStream_t stream) {
    const float* features = (const float*)d_in[0];
    const float* weight   = (const float*)d_in[1];
    const float* bias     = (const float*)d_in[2];
    const void*  edge_idx = d_in[3];
    const float* edge_w   = (const float*)d_in[4];
    int E = in_sizes[4];
    float* out = (float*)d_out;

    char* ws = (char*)d_ws;
    size_t off = 0;
    auto alloc = [&](size_t bytes) -> void* {
        void* p = ws + off;
        off = (off + bytes + 255) & ~(size_t)255;
        return p;
    };
    int*    flag    = (int*)alloc(4);
    int*    bcursor = (int*)alloc(256 * 64);                 // padded counts
    int*    bbase   = (int*)alloc(256 * 4);
    int*    rstart  = (int*)alloc((size_t)(N_NODES + 1) * 4);
    int2*   stage2  = (int2*)alloc((size_t)NBUK * BUK_CAP * 8);
    int2*   ep      = (int2*)alloc((size_t)E * 8);
    short*  Wt      = (short*)alloc((size_t)F_IN * F_OUT * 2);
    __half* H0      = (__half*)alloc((size_t)N_NODES * F_OUT * 2);
    __half* H1      = (__half*)alloc((size_t)N_NODES * F_OUT * 2);

    hipMemsetAsync(bcursor, 0, 256 * 64, stream);

    k_detect<<<1, 64, 0, stream>>>((const int*)edge_idx, flag);
    k_histA<<<196, 1024, 0, stream>>>(edge_idx, edge_w, flag, bcursor, stage2, E);
    k_scanB<<<1, 256, 0, stream>>>(bcursor, bbase, rstart, E);
    k_partB<<<NBUK, 256, 0, stream>>>(bcursor, bbase, stage2, ep, rstart);

    // H0 = tanh(features @ weight)  [bf16 MFMA, K-split, fp16 out]
    k_wconv<<<(F_IN * F_OUT + 255) / 256, 256, 0, stream>>>(weight, Wt);
    k_gemm_mfma<<<(N_NODES + 31) / 32, 256, 0, stream>>>(features, Wt, H0,
                                                         N_NODES);

    // 3 src-sliced SPMM hops; last fuses +bias, writes fp32 d_out
    k_hop<<<HOP_BLOCKS, 256, 0, stream>>>(rstart, ep, (const unsigned*)H0, H1,
                                          bias, 0);
    k_hop<<<HOP_BLOCKS, 256, 0, stream>>>(rstart, ep, (const unsigned*)H1, H0,
                                          bias, 0);
    k_hop<<<HOP_BLOCKS, 256, 0, stream>>>(rstart, ep, (const unsigned*)H0, out,
                                          bias, 1);
}

// Round 9
// 237.290 us; speedup vs baseline: 1.3218x; 1.3218x over previous
//
#include <hip/hip_runtime.h>
#include <hip/hip_bf16.h>
#include <hip/hip_fp16.h>
#include <math.h>

#define N_NODES 50000
#define F_IN 256
#define F_OUT 128
#define NBUK ((N_NODES + 255) >> 8)   // 196 buckets of 256 dsts
#define BUK_CAP 8192                  // >> max bucket edge count (Poisson ~4096)

typedef __attribute__((ext_vector_type(8))) short bf16x8;
typedef __attribute__((ext_vector_type(4))) float f32x4;
typedef _Float16 h2 __attribute__((ext_vector_type(2)));

static __device__ __forceinline__ h2 u2h2(unsigned u) {
    union { unsigned u; h2 h; } x; x.u = u; return x.h;
}
static __device__ __forceinline__ short f2bf(float f) {
    unsigned u = __float_as_uint(f);
    unsigned r = (u + 0x7FFFu + ((u >> 16) & 1u)) >> 16;  // RNE
    return (short)r;
}
static __device__ __forceinline__ float fast_tanh(float x) {
    float e = __expf(2.0f * x);
    return 1.0f - 2.0f / (e + 1.0f);
}

// ---------------------------------------------------------------------------
// K1: detect int64 vs int32 edge_index layout (wave-parallel).
__global__ __launch_bounds__(64) void k_detect(const int* __restrict__ ei,
                                               int* __restrict__ flag) {
    int v = ei[2 * threadIdx.x + 1];
    unsigned long long b = __ballot(v != 0);
    if (threadIdx.x == 0) flag[0] = (b == 0ULL) ? 1 : 0;  // 1 => int64
}

// K2 (fused): decode + pack + block-aggregated append into per-bucket regions.
__global__ __launch_bounds__(1024) void k_histA(const void* __restrict__ ei,
                                                const float* __restrict__ ew,
                                                const int* __restrict__ flag,
                                                int* __restrict__ bcursor,
                                                int2* __restrict__ stage2, int E) {
    __shared__ int hist[NBUK];
    __shared__ int base[NBUK];
    int t = threadIdx.x;
    int isI64 = flag[0];
    for (long long c0 = (long long)blockIdx.x * 4096; c0 < E;
         c0 += (long long)gridDim.x * 4096) {
        if (t < NBUK) hist[t] = 0;
        __syncthreads();
        int2 v[4];
        int b[4], r[4];
        #pragma unroll
        for (int j = 0; j < 4; j++) {
            long long e = c0 + j * 1024 + t;
            if (e < E) {
                int s, d;
                if (isI64) {
                    const long long* p = (const long long*)ei;
                    s = (int)p[e];
                    d = (int)p[(size_t)E + e];
                } else {
                    const int* p = (const int*)ei;
                    s = p[e];
                    d = p[(size_t)E + e];
                }
                unsigned wh = __half_as_ushort(__float2half(ew[e]));
                v[j] = make_int2(s | ((d & 255) << 16) | ((d >> 8) << 24), (int)wh);
                b[j] = d >> 8;
            } else {
                b[j] = -1;
            }
        }
        #pragma unroll
        for (int j = 0; j < 4; j++)
            if (b[j] >= 0) r[j] = atomicAdd(&hist[b[j]], 1);
        __syncthreads();
        if (t < NBUK) {
            int h = hist[t];
            base[t] = h ? atomicAdd(&bcursor[t << 4], h) : 0;
        }
        __syncthreads();
        #pragma unroll
        for (int j = 0; j < 4; j++)
            if (b[j] >= 0)
                stage2[(size_t)b[j] * BUK_CAP + base[b[j]] + r[j]] = v[j];
        __syncthreads();
    }
}

// K3: exclusive scan of 196 bucket counts -> bbase; write rstart[N]=E.
__global__ __launch_bounds__(256) void k_scanB(const int* __restrict__ bcursor,
                                               int* __restrict__ bbase,
                                               int* __restrict__ rstart, int E) {
    __shared__ int sh[256];
    int t = threadIdx.x;
    int c = (t < NBUK) ? bcursor[t << 4] : 0;
    int val = c;
    sh[t] = val;
    __syncthreads();
    for (int off = 1; off < 256; off <<= 1) {
        int x = (t >= off) ? sh[t - off] : 0;
        __syncthreads();
        val += x;
        sh[t] = val;
        __syncthreads();
    }
    if (t < NBUK) bbase[t] = val - c;
    if (t == 0) rstart[N_NODES] = E;
}

// K4: per-bucket: LDS dst-histogram + scan -> rstart, then rank-scatter to ep.
__global__ __launch_bounds__(256) void k_partB(const int* __restrict__ bcursor,
                                               const int* __restrict__ bbase,
                                               const int2* __restrict__ stage2,
                                               int2* __restrict__ ep,
                                               int* __restrict__ rstart) {
    __shared__ int h[256];
    __shared__ int roff[256];
    __shared__ int sh[256];
    int b = blockIdx.x, t = threadIdx.x;
    int cnt = bcursor[b << 4];
    int base = bbase[b];
    const int2* src = stage2 + (size_t)b * BUK_CAP;
    h[t] = 0;
    __syncthreads();
    for (int i = t; i < cnt; i += 256) atomicAdd(&h[(src[i].x >> 16) & 255], 1);
    __syncthreads();
    int c = h[t];
    int val = c;
    sh[t] = val;
    __syncthreads();
    for (int off = 1; off < 256; off <<= 1) {
        int x = (t >= off) ? sh[t - off] : 0;
        __syncthreads();
        val += x;
        sh[t] = val;
        __syncthreads();
    }
    roff[t] = val - c;
    int dst = (b << 8) + t;
    if (dst < N_NODES) rstart[dst] = base + (val - c);
    h[t] = 0;
    __syncthreads();
    for (int i = t; i < cnt; i += 256) {
        int2 v = src[i];
        int dl = (v.x >> 16) & 255;
        int r = atomicAdd(&h[dl], 1);
        ep[base + roff[dl] + r] = make_int2(v.x & 0xFFFF, v.y);
    }
}

// ---------------------------------------------------------------------------
// K5: W[256][128] fp32 -> Wt2 in MFMA-fragment order.
// frag (khalf,k0,j): lane holds bf16x8 = W[khalf*128+k0*32+(lane>>4)*8 + e]
//                                        [j*16 + (lane&15)],  e = 0..7.
// Layout: Wt2[(((khalf*4+k0)*8 + j)*64 + lane)*8 + e]  -> wave reads 1KB
// contiguous per fragment (fully coalesced, L1-hot).
__global__ __launch_bounds__(256) void k_wconv(const float* __restrict__ W,
                                               short* __restrict__ Wt2) {
    int id = blockIdx.x * 256 + threadIdx.x;  // 4096 threads: frag*64 + lane
    int lane = id & 63;
    int frag = id >> 6;       // 0..63 = (khalf*4+k0)*8 + j
    int j = frag & 7;
    int kblk = frag >> 3;     // khalf*4 + k0
    int kbase = kblk * 32 + (lane >> 4) * 8;
    int n = j * 16 + (lane & 15);
    short o[8];
    #pragma unroll
    for (int e = 0; e < 8; e++)
        o[e] = f2bf(W[(size_t)(kbase + e) * F_OUT + n]);
    #pragma unroll
    for (int e = 0; e < 8; e++) Wt2[(size_t)id * 8 + e] = o[e];
}

// K6: H[M,128] = tanh(A[M,256] @ W) via bf16 MFMA, fp16 out.
// K-split 2-way (4 waves: rowhalf x khalf), full A-strip prefetch,
// fragment-ordered B loads (coalesced).
#define RED_STRIDE 36
__global__ __launch_bounds__(256) void k_gemm_mfma(const float* __restrict__ A,
                                                   const short* __restrict__ Wt2,
                                                   __half* __restrict__ H, int M) {
    __shared__ float red[2 * 64 * RED_STRIDE];  // 18.4 KB
    int wave = threadIdx.x >> 6;
    int lane = threadIdx.x & 63;
    int lm = lane & 15;
    int kgrp = lane >> 4;
    int rowhalf = wave >> 1;
    int khalf = wave & 1;
    int m = blockIdx.x * 32 + rowhalf * 16 + lm;
    int am = (m < M) ? m : (M - 1);
    const float* arow = A + (size_t)am * F_IN + khalf * 128 + kgrp * 8;

    float4 a[8];
    #pragma unroll
    for (int k0 = 0; k0 < 4; k0++) {
        a[2 * k0]     = *(const float4*)(arow + k0 * 32);
        a[2 * k0 + 1] = *(const float4*)(arow + k0 * 32 + 4);
    }

    f32x4 acc[8] = {};
    #pragma unroll
    for (int k0 = 0; k0 < 4; k0++) {
        bf16x8 af;
        af[0] = f2bf(a[2 * k0].x);     af[1] = f2bf(a[2 * k0].y);
        af[2] = f2bf(a[2 * k0].z);     af[3] = f2bf(a[2 * k0].w);
        af[4] = f2bf(a[2 * k0 + 1].x); af[5] = f2bf(a[2 * k0 + 1].y);
        af[6] = f2bf(a[2 * k0 + 1].z); af[7] = f2bf(a[2 * k0 + 1].w);
        const short* wb = Wt2 + (size_t)(((khalf * 4 + k0) * 8) * 64 + lane) * 8;
        #pragma unroll
        for (int j = 0; j < 8; j++) {
            bf16x8 bf = *(const bf16x8*)(wb + (size_t)j * 512);
            acc[j] = __builtin_amdgcn_mfma_f32_16x16x32_bf16(af, bf, acc[j], 0, 0, 0);
        }
    }

    float* myred = &red[(rowhalf * 64 + lane) * RED_STRIDE];
    if (khalf == 1) {
        #pragma unroll
        for (int j = 0; j < 8; j++) *(f32x4*)(myred + j * 4) = acc[j];
    }
    __syncthreads();
    if (khalf == 0) {
        int rbase = blockIdx.x * 32 + rowhalf * 16 + kgrp * 4;
        #pragma unroll
        for (int j = 0; j < 8; j++) {
            f32x4 o = *(const f32x4*)(myred + j * 4);
            #pragma unroll
            for (int jj = 0; jj < 4; jj++) {
                int r = rbase + jj;
                if (r < M)
                    H[(size_t)r * F_OUT + j * 16 + lm] =
                        __float2half(fast_tanh(acc[j][jj] + o[jj]));
            }
        }
    }
}

// ---------------------------------------------------------------------------
// K7: SPMM hop (round-7 form). Wave handles 2 nodes; lane owns cols {2l,2l+1}.
// 4x unroll per node: 8 independent row-gathers issued before the 16 dot2s.
__global__ __launch_bounds__(256) void k_hop(const int* __restrict__ rstart,
                                             const int2* __restrict__ ep,
                                             const unsigned* __restrict__ xin,
                                             void* __restrict__ xoutv,
                                             const float* __restrict__ bias,
                                             int last) {
    int pair = blockIdx.x * 4 + (threadIdx.x >> 6);
    int widA = pair * 2;
    if (widA >= N_NODES) return;
    int widB = widA + 1;
    bool hasB = widB < N_NODES;
    int lane = threadIdx.x & 63;
    int sA = rstart[widA], eA = rstart[widA + 1];
    int sB = hasB ? rstart[widB] : 0;
    int eB = hasB ? rstart[widB + 1] : 0;
    float axA = 0.f, ayA = 0.f, axB = 0.f, ayB = 0.f;

#define GATHER(ev, j) \
    xin[(size_t)(unsigned)__builtin_amdgcn_readlane((ev).x, (j)) * 64 + lane]
#define DOT(hv, wj, ax, ay) {                                               \
        h2 h_ = u2h2(hv);                                                   \
        ax = __builtin_amdgcn_fdot2(h_, u2h2((unsigned)(wj)), ax, false);   \
        ay = __builtin_amdgcn_fdot2(h_, u2h2(((unsigned)(wj)) << 16), ay, false); }
#define EDGE1(ev, j, ax, ay) {                                              \
        unsigned hv_ = GATHER(ev, j);                                       \
        int wj_ = __builtin_amdgcn_readlane((ev).y, (j));                   \
        DOT(hv_, wj_, ax, ay) }

    while (sA < eA || sB < eB) {
        int nA = eA - sA; nA = (nA > 64) ? 64 : (nA < 0 ? 0 : nA);
        int nB = eB - sB; nB = (nB > 64) ? 64 : (nB < 0 ? 0 : nB);
        int2 evA = (lane < nA) ? ep[sA + lane] : make_int2(0, 0);
        int2 evB = (lane < nB) ? ep[sB + lane] : make_int2(0, 0);
        int m = (nA < nB) ? nA : nB;
        int i = 0;
        for (; i + 4 <= m; i += 4) {
            unsigned va0 = GATHER(evA, i);
            unsigned va1 = GATHER(evA, i + 1);
            unsigned va2 = GATHER(evA, i + 2);
            unsigned va3 = GATHER(evA, i + 3);
            unsigned vb0 = GATHER(evB, i);
            unsigned vb1 = GATHER(evB, i + 1);
            unsigned vb2 = GATHER(evB, i + 2);
            unsigned vb3 = GATHER(evB, i + 3);
            int wa0 = __builtin_amdgcn_readlane(evA.y, i);
            int wa1 = __builtin_amdgcn_readlane(evA.y, i + 1);
            int wa2 = __builtin_amdgcn_readlane(evA.y, i + 2);
            int wa3 = __builtin_amdgcn_readlane(evA.y, i + 3);
            int wb0 = __builtin_amdgcn_readlane(evB.y, i);
            int wb1 = __builtin_amdgcn_readlane(evB.y, i + 1);
            int wb2 = __builtin_amdgcn_readlane(evB.y, i + 2);
            int wb3 = __builtin_amdgcn_readlane(evB.y, i + 3);
            DOT(va0, wa0, axA, ayA)
            DOT(va1, wa1, axA, ayA)
            DOT(va2, wa2, axA, ayA)
            DOT(va3, wa3, axA, ayA)
            DOT(vb0, wb0, axB, ayB)
            DOT(vb1, wb1, axB, ayB)
            DOT(vb2, wb2, axB, ayB)
            DOT(vb3, wb3, axB, ayB)
        }
        for (; i < m; i++) { EDGE1(evA, i, axA, ayA) EDGE1(evB, i, axB, ayB) }
        for (int j = i; j < nA; j++) EDGE1(evA, j, axA, ayA)
        for (int j = i; j < nB; j++) EDGE1(evB, j, axB, ayB)
        sA += nA;
        sB += nB;
    }
#undef EDGE1
#undef DOT
#undef GATHER

    if (last) {
        float bx = bias[2 * lane], by = bias[2 * lane + 1];
        float2* o = (float2*)xoutv;
        o[(size_t)widA * 64 + lane] = make_float2(axA + bx, ayA + by);
        if (hasB) o[(size_t)widB * 64 + lane] = make_float2(axB + bx, ayB + by);
    } else {
        __half2* o = (__half2*)xoutv;
        o[(size_t)widA * 64 + lane] = __floats2half2_rn(axA, ayA);
        if (hasB) o[(size_t)widB * 64 + lane] = __floats2half2_rn(axB, ayB);
    }
}

// ---------------------------------------------------------------------------
extern "C" void kernel_launch(void* const* d_in, const int* in_sizes, int n_in,
                              void* d_out, int out_size, void* d_ws, size_t ws_size,
                              hipStream_t stream) {
    const float* features = (const float*)d_in[0];
    const float* weight   = (const float*)d_in[1];
    const float* bias     = (const float*)d_in[2];
    const void*  edge_idx = d_in[3];
    const float* edge_w   = (const float*)d_in[4];
    int E = in_sizes[4];
    float* out = (float*)d_out;

    char* ws = (char*)d_ws;
    size_t off = 0;
    auto alloc = [&](size_t bytes) -> void* {
        void* p = ws + off;
        off = (off + bytes + 255) & ~(size_t)255;
        return p;
    };
    int*    flag    = (int*)alloc(4);
    int*    bcursor = (int*)alloc(256 * 64);                 // padded counts
    int*    bbase   = (int*)alloc(256 * 4);
    int*    rstart  = (int*)alloc((size_t)(N_NODES + 1) * 4);
    int2*   stage2  = (int2*)alloc((size_t)NBUK * BUK_CAP * 8);
    int2*   ep      = (int2*)alloc((size_t)E * 8);
    short*  Wt2     = (short*)alloc((size_t)F_IN * F_OUT * 2);
    __half* H0      = (__half*)alloc((size_t)N_NODES * F_OUT * 2);
    __half* H1      = (__half*)alloc((size_t)N_NODES * F_OUT * 2);

    hipMemsetAsync(bcursor, 0, 256 * 64, stream);

    k_detect<<<1, 64, 0, stream>>>((const int*)edge_idx, flag);
    k_histA<<<196, 1024, 0, stream>>>(edge_idx, edge_w, flag, bcursor, stage2, E);
    k_scanB<<<1, 256, 0, stream>>>(bcursor, bbase, rstart, E);
    k_partB<<<NBUK, 256, 0, stream>>>(bcursor, bbase, stage2, ep, rstart);

    // H0 = tanh(features @ weight)  [bf16 MFMA, K-split, frag-ordered B]
    k_wconv<<<16, 256, 0, stream>>>(weight, Wt2);
    k_gemm_mfma<<<(N_NODES + 31) / 32, 256, 0, stream>>>(features, Wt2, H0,
                                                         N_NODES);

    // 3 SPMM hops; last fuses +bias, writes fp32 d_out
    int hop_blocks = (25000 + 3) / 4;  // ceil(N/2) pairs, 4 waves/block
    k_hop<<<hop_blocks, 256, 0, stream>>>(rstart, ep, (const unsigned*)H0, H1,
                                          bias, 0);
    k_hop<<<hop_blocks, 256, 0, stream>>>(rstart, ep, (const unsigned*)H1, H0,
                                          bias, 0);
    k_hop<<<hop_blocks, 256, 0, stream>>>(rstart, ep, (const unsigned*)H0, out,
                                          bias, 1);
}